// Round 12
// baseline (281.078 us; speedup 1.0000x reference)
//
#include <hip/hip_runtime.h>

#define B_  128
#define N_  32
#define L_  36
#define DS  512
#define DV  1024
#define H_  512
#define P_  496
#define R_  63488      // B_*P_

typedef __attribute__((ext_vector_type(8))) short bf16x8;
typedef __attribute__((ext_vector_type(4))) float f32x4;
typedef __attribute__((ext_vector_type(16))) float f32x16;

__device__ __forceinline__ ushort f2bf(float x){
  unsigned u = __builtin_bit_cast(unsigned, x);
  return (ushort)((u + 0x7FFFu + ((u >> 16) & 1u)) >> 16);
}
__device__ __forceinline__ float bf2f(ushort u){
  unsigned v = ((unsigned)u) << 16;
  return __builtin_bit_cast(float, v);
}

// elementwise bf16 product (f32 mul, RNE round)
__device__ __forceinline__ bf16x8 pkmul(bf16x8 a, bf16x8 b){
  bf16x8 o;
  #pragma unroll
  for (int e = 0; e < 8; ++e)
    o[e] = (short)f2bf(bf2f((ushort)a[e]) * bf2f((ushort)b[e]));
  return o;
}

__device__ __forceinline__ void gload16(const void* g, void* l){
  __builtin_amdgcn_global_load_lds((const __attribute__((address_space(1))) unsigned*)g,
                                   (__attribute__((address_space(3))) unsigned*)l, 16, 0, 0);
}

__device__ __forceinline__ float wave_sum(float v){
  #pragma unroll
  for (int m = 32; m >= 1; m >>= 1) v += __shfl_xor(v, m);
  return v;
}
__device__ __forceinline__ float wave_max(float v){
  #pragma unroll
  for (int m = 32; m >= 1; m >>= 1) v = fmaxf(v, __shfl_xor(v, m));
  return v;
}

// ---------- merged prep: conv(span,img->bf16, text init) + 5 transposes + setup ----------
#define SPAN_F4 524288        // 4096*512/4
#define IMG_F4  1179648       // 128*36*1024/4
#define CONV_BLKS ((SPAN_F4 + IMG_F4) / 256)   // 6656
#define TR_BLKS   (512 * 5)                    // 2560
__global__ void prep_all(const float* __restrict__ span, const float* __restrict__ img,
                         const float* __restrict__ b3,
                         const float* __restrict__ Wg, const float* __restrict__ W1,
                         const float* __restrict__ W2,
                         const float* __restrict__ sm, const float* __restrict__ im,
                         ushort* __restrict__ spbf, ushort* __restrict__ imgbf,
                         float* __restrict__ text,
                         ushort* __restrict__ WgT, ushort* __restrict__ UVBT,
                         ushort* __restrict__ W1cT, ushort* __restrict__ W2T,
                         float* cnt_s, float* cnt_i, int* iu, int* ju, float* loss){
  __shared__ float tile[32][33];
  const int bid = blockIdx.x, tid = threadIdx.x;
  if (bid < CONV_BLKS){
    int idx = bid * 256 + tid;
    if (idx < R_) text[idx] = b3[0];
    const float* src; ushort* dst; int k;
    if (idx < SPAN_F4){ src = span; dst = spbf; k = idx; }
    else              { src = img;  dst = imgbf; k = idx - SPAN_F4; }
    float4 v = *(const float4*)&src[(size_t)k * 4];
    ushort4 o; o.x = f2bf(v.x); o.y = f2bf(v.y); o.z = f2bf(v.z); o.w = f2bf(v.w);
    *(ushort4*)&dst[(size_t)k * 4] = o;
  } else if (bid < CONV_BLKS + TR_BLKS){
    int b = bid - CONV_BLKS;
    int z = b >> 9, rem = b & 511;
    int bx = rem & 31, by = rem >> 5;
    const float* src; ushort* dst; int Nn;
    if      (z == 0){ src = Wg;            dst = WgT;            Nn = 1024; }
    else if (z == 1){ src = W1;            dst = UVBT;           Nn = 512;  }
    else if (z == 2){ src = W1 + 512*512;  dst = UVBT + 512*512; Nn = 512;  }
    else if (z == 3){ src = W1 + 1024*512; dst = W1cT;           Nn = 512;  }
    else            { src = W2;            dst = W2T;            Nn = 512;  }
    if (bx * 32 >= Nn) return;
    int n0 = bx * 32, k0 = by * 32;
    int x = tid & 31, y = tid >> 5;   // 32 x 8
    #pragma unroll
    for (int i = 0; i < 4; ++i) tile[y + 8*i][x] = src[(k0 + y + 8*i) * Nn + n0 + x];
    __syncthreads();
    #pragma unroll
    for (int i = 0; i < 4; ++i) dst[(n0 + y + 8*i) * 512 + k0 + x] = f2bf(tile[x][y + 8*i]);
  } else {
    int t = (bid - CONV_BLKS - TR_BLKS) * 256 + tid;   // [0,512)
    if (t < P_){
      int i = 0, rem = t, cnt = N_ - 1;
      while (rem >= cnt){ rem -= cnt; ++i; --cnt; }
      iu[t] = i; ju[t] = i + 1 + rem;
    }
    if (t < B_){
      float s = 0.f;
      for (int n = 0; n < N_; ++n) s += sm[t*N_ + n];
      cnt_s[t] = s;
    } else if (t < 2*B_){
      int j = t - B_;
      float s = 0.f;
      for (int l = 0; l < L_; ++l) s += im[j*L_ + l];
      cnt_i[j] = s;
    }
    if (t == 0) loss[0] = 0.f;
  }
}

// ---------- shared bf16 MFMA mainloop (LDS-staged, 128x128 tile, BK=32; for span GEMMs) ----------
__device__ __forceinline__ void mma_mainloop(const ushort* __restrict__ A,
                                             const ushort* __restrict__ BT,
                                             size_t m0, int n0,
                                             ushort* sA, ushort* sB, f32x4 acc[4][4]){
  const int tid = threadIdx.x, wid = tid >> 6, lane = tid & 63;
  const int wm = (wid >> 1) * 64, wn = (wid & 1) * 64;
  const int quad = lane >> 4, fm = lane & 15;
  const char* gA = (const char*)A + (m0 + (size_t)(wid * 32 + (lane >> 2))) * 1024 + (lane & 3) * 16;
  const char* gB = (const char*)BT + ((size_t)n0 + wid * 32 + (lane >> 2)) * 1024 + (lane & 3) * 16;
  ushort* lA = sA + wid * 32 * 32;
  ushort* lB = sB + wid * 32 * 32;
  #pragma unroll 1
  for (int ks = 0; ks < 16; ++ks){
    gload16(gA,             lA);
    gload16(gA + 16 * 1024, lA + 16 * 32);
    gload16(gB,             lB);
    gload16(gB + 16 * 1024, lB + 16 * 32);
    __syncthreads();
    bf16x8 af[4], bg[4];
    #pragma unroll
    for (int i = 0; i < 4; ++i){
      af[i] = *(const bf16x8*)&sA[(wm + i * 16 + fm) * 32 + quad * 8];
      bg[i] = *(const bf16x8*)&sB[(wn + i * 16 + fm) * 32 + quad * 8];
    }
    #pragma unroll
    for (int i = 0; i < 4; ++i)
      #pragma unroll
      for (int j = 0; j < 4; ++j)
        acc[i][j] = __builtin_amdgcn_mfma_f32_16x16x32_bf16(af[i], bg[j], acc[i][j], 0, 0, 0);
    __syncthreads();
    gA += 64; gB += 64;
  }
}

// Merged: span GEMMs ([SGbf|UVbf] = spbf @ [WgT;UVBT], blocks 0..511) + make_z (blocks 512+)
__global__ __launch_bounds__(256) void span2_makez(const ushort* __restrict__ A,
                                                   const ushort* __restrict__ BT2,
                                                   ushort* __restrict__ SG,
                                                   ushort* __restrict__ UV,
                                                   const int* __restrict__ iu,
                                                   const int* __restrict__ ju,
                                                   ushort* __restrict__ Z){
  __shared__ ushort sA[4096], sB[4096];
  if (blockIdx.x < 512){
    f32x4 acc[4][4] = {};
    size_t m0 = (size_t)(blockIdx.x >> 4) * 128;
    int ng = (blockIdx.x & 15) * 128;
    mma_mainloop(A, BT2, m0, ng, sA, sB, acc);
    const int tid = threadIdx.x, wid = tid >> 6, lane = tid & 63;
    const int wm = (wid >> 1) * 64, wn = (wid & 1) * 64, quad = lane >> 4, fm = lane & 15;
    ushort* C = (ng < 1024) ? SG : UV;
    const int nbase = (ng < 1024) ? ng : (ng - 1024);
    #pragma unroll
    for (int i = 0; i < 4; ++i)
      #pragma unroll
      for (int r = 0; r < 4; ++r){
        size_t row = m0 + wm + i * 16 + quad * 4 + r;
        #pragma unroll
        for (int j = 0; j < 4; ++j){
          int col = nbase + wn + j * 16 + fm;
          C[row * 1024 + col] = f2bf(acc[i][j][r]);
        }
      }
  } else {
    int idx = (blockIdx.x - 512) * 256 + threadIdx.x;  // 8 elems each
    int r = idx >> 6, k = (idx & 63) << 3;
    int b = r / P_, p = r - b * P_;
    bf16x8 x = *(const bf16x8*)&A[(size_t)(b * N_ + iu[p]) * 512 + k];
    bf16x8 y = *(const bf16x8*)&A[(size_t)(b * N_ + ju[p]) * 512 + k];
    *(bf16x8*)&Z[(size_t)r * 512 + k] = pkmul(x, y);
  }
}

// M[b] = SGbf[b] @ imgbf[b]^T; also Msum[b,:] and Mtot[b]
__global__ __launch_bounds__(256) void batched_m_mfma(const ushort* __restrict__ SGbf,
                                                      const ushort* __restrict__ imgbf,
                                                      const float* __restrict__ sm,
                                                      float* __restrict__ Mout,
                                                      float* __restrict__ Msum,
                                                      float* __restrict__ Mtot){
  const int b = blockIdx.x;
  const int tid = threadIdx.x, wid = tid >> 6, lane = tid & 63;
  const int quad = lane >> 4, fm = lane & 15;
  __shared__ float red[4][32][48];
  __shared__ float shr[4];
  f32x4 acc[2][3] = {};
  const int wk = wid * 256;
  const ushort* Ab = SGbf + (size_t)b * 32 * 1024;
  const ushort* Bb = imgbf + (size_t)b * 36 * 1024;
  #pragma unroll
  for (int ks = 0; ks < 8; ++ks){
    const int k = wk + ks * 32 + quad * 8;
    bf16x8 af[2], bg[3];
    af[0] = *(const bf16x8*)&Ab[(0*16 + fm) * 1024 + k];
    af[1] = *(const bf16x8*)&Ab[(1*16 + fm) * 1024 + k];
    bg[0] = *(const bf16x8*)&Bb[(0*16 + fm) * 1024 + k];
    bg[1] = *(const bf16x8*)&Bb[(1*16 + fm) * 1024 + k];
    bg[2] = *(const bf16x8*)&Bb[(2*16 + fm) * 1024 + k];  // rows 36..47 slack
    #pragma unroll
    for (int i = 0; i < 2; ++i)
      #pragma unroll
      for (int j = 0; j < 3; ++j)
        acc[i][j] = __builtin_amdgcn_mfma_f32_16x16x32_bf16(af[i], bg[j], acc[i][j], 0, 0, 0);
  }
  #pragma unroll
  for (int i = 0; i < 2; ++i)
    #pragma unroll
    for (int j = 0; j < 3; ++j)
      #pragma unroll
      for (int r = 0; r < 4; ++r)
        red[wid][i*16 + quad*4 + r][j*16 + fm] = acc[i][j][r];
  __syncthreads();
  float tot = 0.f;
  #pragma unroll
  for (int q = 0; q < 5; ++q){
    int out = tid + 256 * q;
    if (out < N_*L_){
      int n = out / L_, l = out - n * L_;
      float v = red[0][n][l] + red[1][n][l] + red[2][n][l] + red[3][n][l];
      Mout[b * (N_*L_) + out] = v;
      tot += v;
    }
  }
  tot = wave_sum(tot);
  if (lane == 0) shr[wid] = tot;
  __syncthreads();
  if (tid == 0) Mtot[b] = shr[0] + shr[1] + shr[2] + shr[3];
  if (tid < L_){
    float s = 0.f;
    for (int n = 0; n < N_; ++n){
      float mv = red[0][n][tid] + red[1][n][tid] + red[2][n][tid] + red[3][n][tid];
      s += mv * sm[b*N_ + n];
    }
    Msum[b*L_ + tid] = s;
  }
}

// logsumexp over rows+cols with sent computed on the fly from Msum; atomic loss add
__global__ void lse_loss(const float* __restrict__ Msum, const float* __restrict__ im,
                         const float* __restrict__ cnt_s, const float* __restrict__ cnt_i,
                         const float* __restrict__ Mtot, float* __restrict__ out){
  const int i = blockIdx.x, t = threadIdx.x;  // 128 threads = 2 waves
  const int wid = t >> 6, lane = t & 63;
  __shared__ float sh[2];
  float sr = 0.f, sc = 0.f;
  #pragma unroll 4
  for (int l = 0; l < L_; ++l){
    sr += Msum[i*L_ + l] * im[t*L_ + l];
    sc += Msum[t*L_ + l] * im[i*L_ + l];
  }
  const float dr = cnt_s[i] * cnt_i[t];
  const float vr = (dr != 0.f) ? (sr / dr) : (Mtot[i] * (1.f/(float)(N_*L_)));
  const float dc = cnt_s[t] * cnt_i[i];
  const float vc = (dc != 0.f) ? (sc / dc) : (Mtot[t] * (1.f/(float)(N_*L_)));

  float m = wave_max(vr);
  if (lane == 0) sh[wid] = m;
  __syncthreads();
  const float mr = fmaxf(sh[0], sh[1]);
  __syncthreads();
  float e = wave_sum(expf(vr - mr));
  if (lane == 0) sh[wid] = e;
  __syncthreads();
  const float ser = sh[0] + sh[1];
  __syncthreads();
  float rs = wave_sum(vr);
  if (lane == 0) sh[wid] = rs;
  __syncthreads();
  const float rst = sh[0] + sh[1];
  __syncthreads();
  float mc0 = wave_max(vc);
  if (lane == 0) sh[wid] = mc0;
  __syncthreads();
  const float mc = fmaxf(sh[0], sh[1]);
  __syncthreads();
  float ec = wave_sum(expf(vc - mc));
  if (lane == 0) sh[wid] = ec;
  __syncthreads();
  const float sec = sh[0] + sh[1];
  if (t == 0){
    float contrib = (mr + logf(ser)) + (mc + logf(sec)) - 2.f * rst / (float)B_;
    atomicAdd(out, contrib);
  }
}

// ---------- BK=64 mainloop, 32x32x16 MFMA: 16 MFMA + 16 ds_read_b128 per barrier-pair ----------
// A-frag: A[m = lane&31][k = (lane>>5)*8 + j]; B-frag: B[k][n = lane&31], same k mapping.
__device__ __forceinline__ void mma_loop_k64_w32(const ushort* __restrict__ A,
                                                 const ushort* __restrict__ BT,
                                                 size_t m0, int n0,
                                                 ushort* sA0, ushort* sA1,
                                                 ushort* sB0, ushort* sB1,
                                                 f32x16 acc[2][2]){
  const int tid = threadIdx.x, wid = tid >> 6, lane = tid & 63;
  const int wm = (wid >> 1) * 64, wn = (wid & 1) * 64;
  const int half = lane >> 5, l31 = lane & 31;
  const int r64 = tid >> 2, ch = (tid & 3) * 8;
  const ushort* gA = A + (m0 + r64) * 512 + ch;
  const ushort* gB = BT + (size_t)(n0 + r64) * 512 + ch;
  #pragma unroll 1
  for (int ks = 0; ks < 8; ++ks){
    const int k0 = ks * 64;
    gload16(gA + k0,                 sA0 + tid * 8);
    gload16(gA + 64 * 512 + k0,      sA0 + 2048 + tid * 8);
    gload16(gA + k0 + 32,            sA1 + tid * 8);
    gload16(gA + 64 * 512 + k0 + 32, sA1 + 2048 + tid * 8);
    gload16(gB + k0,                 sB0 + tid * 8);
    gload16(gB + 64 * 512 + k0,      sB0 + 2048 + tid * 8);
    gload16(gB + k0 + 32,            sB1 + tid * 8);
    gload16(gB + 64 * 512 + k0 + 32, sB1 + 2048 + tid * 8);
    __syncthreads();
    #pragma unroll
    for (int km = 0; km < 2; ++km){
      bf16x8 af[2], bg[2];
      af[0] = *(const bf16x8*)&sA0[(wm + l31)      * 32 + km * 16 + half * 8];
      af[1] = *(const bf16x8*)&sA0[(wm + 32 + l31) * 32 + km * 16 + half * 8];
      bg[0] = *(const bf16x8*)&sB0[(wn + l31)      * 32 + km * 16 + half * 8];
      bg[1] = *(const bf16x8*)&sB0[(wn + 32 + l31) * 32 + km * 16 + half * 8];
      #pragma unroll
      for (int i = 0; i < 2; ++i)
        #pragma unroll
        for (int j = 0; j < 2; ++j)
          acc[i][j] = __builtin_amdgcn_mfma_f32_32x32x16_bf16(af[i], bg[j], acc[i][j], 0, 0, 0);
    }
    #pragma unroll
    for (int km = 0; km < 2; ++km){
      bf16x8 af[2], bg[2];
      af[0] = *(const bf16x8*)&sA1[(wm + l31)      * 32 + km * 16 + half * 8];
      af[1] = *(const bf16x8*)&sA1[(wm + 32 + l31) * 32 + km * 16 + half * 8];
      bg[0] = *(const bf16x8*)&sB1[(wn + l31)      * 32 + km * 16 + half * 8];
      bg[1] = *(const bf16x8*)&sB1[(wn + 32 + l31) * 32 + km * 16 + half * 8];
      #pragma unroll
      for (int i = 0; i < 2; ++i)
        #pragma unroll
        for (int j = 0; j < 2; ++j)
          acc[i][j] = __builtin_amdgcn_mfma_f32_32x32x16_bf16(af[i], bg[j], acc[i][j], 0, 0, 0);
    }
    __syncthreads();
  }
}

// XCD-aware tile mapping: all 4 n-tiles of an m-tile land on the same XCD, adjacent in time.
__device__ __forceinline__ void tile_map(int bid, int& m0, int& n0){
  int x = bid & 7;
  int q = bid >> 3;        // 0..247
  int m = x * 62 + (q >> 2);
  m0 = m * 128;
  n0 = (q & 3) * 128;
}

// h1 = relu(Z@W1c + U + V + b1), bf16 out. 128x128 tile, BK=64, 32x32x16 MFMA.
// C/D: col = lane&31 (+32*j), row = (reg&3) + 8*(reg>>2) + 4*(lane>>5) (+32*i).
__global__ __launch_bounds__(256, 5) void gemm_z(const ushort* __restrict__ Z,
                                                 const ushort* __restrict__ W1cT,
                                                 const ushort* __restrict__ UV,
                                                 const float* __restrict__ b1,
                                                 const int* __restrict__ iu,
                                                 const int* __restrict__ ju,
                                                 ushort* __restrict__ h1){
  __shared__ ushort sA0[4096], sA1[4096], sB0[4096], sB1[4096];  // 32 KB
  f32x16 acc[2][2] = {};
  int m0i, n0; tile_map(blockIdx.x, m0i, n0);
  const size_t m0 = (size_t)m0i;
  mma_loop_k64_w32(Z, W1cT, m0, n0, sA0, sA1, sB0, sB1, acc);
  const int tid = threadIdx.x, wid = tid >> 6, lane = tid & 63;
  const int wm = (wid >> 1) * 64, wn = (wid & 1) * 64;
  const int half = lane >> 5, l31 = lane & 31;
  float b1v[2];
  #pragma unroll
  for (int j = 0; j < 2; ++j) b1v[j] = b1[n0 + wn + j * 32 + l31];
  #pragma unroll
  for (int i = 0; i < 2; ++i)
    #pragma unroll
    for (int reg = 0; reg < 16; ++reg){
      int row = (int)m0 + wm + i * 32 + (reg & 3) + 8 * (reg >> 2) + 4 * half;
      int b = row / P_, p = row - b * P_;
      const ushort* Ur = UV + (size_t)(b * N_ + iu[p]) * 1024;
      const ushort* Vr = UV + (size_t)(b * N_ + ju[p]) * 1024 + 512;
      #pragma unroll
      for (int j = 0; j < 2; ++j){
        int col = n0 + wn + j * 32 + l31;
        float h = acc[i][j][reg] + bf2f(Ur[col]) + bf2f(Vr[col]) + b1v[j];
        h1[(size_t)row * 512 + col] = f2bf(fmaxf(h, 0.f));
      }
    }
}

// text += sum_col relu(h1@W2 + b2) * W3. 128x128 tile, BK=64, 32x32x16 MFMA.
__global__ __launch_bounds__(256, 5) void gemm_h2(const ushort* __restrict__ h1,
                                                  const ushort* __restrict__ W2T,
                                                  const float* __restrict__ b2,
                                                  const float* __restrict__ W3,
                                                  float* __restrict__ text){
  __shared__ ushort sA0[4096], sA1[4096], sB0[4096], sB1[4096];  // 32 KB
  f32x16 acc[2][2] = {};
  int m0i, n0; tile_map(blockIdx.x, m0i, n0);
  const size_t m0 = (size_t)m0i;
  mma_loop_k64_w32(h1, W2T, m0, n0, sA0, sA1, sB0, sB1, acc);
  const int tid = threadIdx.x, wid = tid >> 6, lane = tid & 63;
  const int wm = (wid >> 1) * 64, wn = (wid & 1) * 64;
  const int half = lane >> 5, l31 = lane & 31;
  float w3v[2], b2v[2];
  #pragma unroll
  for (int j = 0; j < 2; ++j){
    int col = n0 + wn + j * 32 + l31;
    w3v[j] = W3[col]; b2v[j] = b2[col];
  }
  #pragma unroll
  for (int i = 0; i < 2; ++i)
    #pragma unroll
    for (int reg = 0; reg < 16; ++reg){
      int row = (int)m0 + wm + i * 32 + (reg & 3) + 8 * (reg >> 2) + 4 * half;
      float s = 0.f;
      #pragma unroll
      for (int j = 0; j < 2; ++j){
        float h = fmaxf(acc[i][j][reg] + b2v[j], 0.f);
        s = fmaf(h, w3v[j], s);
      }
      // reduce across the 32 col-lanes (l31); both half-waves reduce their own row set
      s += __shfl_xor(s, 1); s += __shfl_xor(s, 2); s += __shfl_xor(s, 4);
      s += __shfl_xor(s, 8); s += __shfl_xor(s, 16);
      if (l31 == 0) atomicAdd(&text[row], s);
    }
}

extern "C" void kernel_launch(void* const* d_in, const int* in_sizes, int n_in,
                              void* d_out, int out_size, void* d_ws, size_t ws_size,
                              hipStream_t stream) {
  const float* span = (const float*)d_in[0];
  const float* img  = (const float*)d_in[1];
  const float* sm   = (const float*)d_in[2];
  const float* im   = (const float*)d_in[3];
  const float* Wg   = (const float*)d_in[4];
  const float* W1   = (const float*)d_in[5];
  const float* b1   = (const float*)d_in[6];
  const float* W2   = (const float*)d_in[7];
  const float* b2   = (const float*)d_in[8];
  const float* W3   = (const float*)d_in[9];
  const float* b3   = (const float*)d_in[10];

  float* out  = (float*)d_out;
  float* loss = out;
  float* Mout = out + 1;
  float* text = out + 1 + B_*N_*L_;

  ushort* wsu  = (ushort*)d_ws;
  ushort* Zbf  = wsu;                          // R_*512
  ushort* h1bf = Zbf + (size_t)R_*512;         // R_*512
  ushort* UVbf = h1bf + (size_t)R_*512;        // 4096*1024
  ushort* SGbf = UVbf + (size_t)4096*1024;     // 4096*1024
  ushort* spbf = SGbf + (size_t)4096*1024;     // 4096*512
  ushort* imgbf= spbf + 4096*512;              // (128*36+12)*1024
  ushort* BT2  = imgbf + (size_t)(B_*L_ + 12)*1024; // WgT (1024*512) then UVBT (1024*512)
  ushort* WgT  = BT2;
  ushort* UVBT = BT2 + 1024*512;
  ushort* W1cT = UVBT + 1024*512;              // 512*512
  ushort* W2T  = W1cT + 512*512;               // 512*512
  float* Msum  = (float*)(W2T + 512*512);      // 4608
  float* Mtot  = Msum + B_*L_;
  float* cnt_s = Mtot + B_;
  float* cnt_i = cnt_s + B_;
  int*   iu    = (int*)(cnt_i + B_);           // 496
  int*   ju    = iu + P_;                      // 496

  prep_all<<<CONV_BLKS + TR_BLKS + 2, 256, 0, stream>>>(
      span, img, b3, Wg, W1, W2, sm, im,
      spbf, imgbf, text, WgT, UVBT, W1cT, W2T, cnt_s, cnt_i, iu, ju, loss);

  // span GEMMs + make_z in one dispatch
  span2_makez<<<512 + R_*512/8/256, 256, 0, stream>>>(spbf, BT2, SGbf, UVbf, iu, ju, Zbf);

  // M / loss path
  batched_m_mfma<<<B_, 256, 0, stream>>>(SGbf, imgbf, sm, Mout, Msum, Mtot);
  lse_loss<<<B_, B_, 0, stream>>>(Msum, im, cnt_s, cnt_i, Mtot, loss);

  // text path: two 128x128 BK=64 GEMMs, 32x32x16 MFMA, XCD-swizzled
  gemm_z <<<1984, 256, 0, stream>>>(Zbf, W1cT, UVbf, b1, iu, ju, h1bf);
  gemm_h2<<<1984, 256, 0, stream>>>(h1bf, W2T, b2, W3, text);
}

// Round 13
// 267.931 us; speedup vs baseline: 1.0491x; 1.0491x over previous
//
#include <hip/hip_runtime.h>

#define B_  128
#define N_  32
#define L_  36
#define DS  512
#define DV  1024
#define H_  512
#define P_  496
#define R_  63488      // B_*P_
#define GEMM_BLKS 1984

typedef __attribute__((ext_vector_type(8))) short bf16x8;
typedef __attribute__((ext_vector_type(4))) float f32x4;

__device__ __forceinline__ ushort f2bf(float x){
  unsigned u = __builtin_bit_cast(unsigned, x);
  return (ushort)((u + 0x7FFFu + ((u >> 16) & 1u)) >> 16);
}
__device__ __forceinline__ float bf2f(ushort u){
  unsigned v = ((unsigned)u) << 16;
  return __builtin_bit_cast(float, v);
}

__device__ __forceinline__ bf16x8 pkmul(bf16x8 a, bf16x8 b){
  bf16x8 o;
  #pragma unroll
  for (int e = 0; e < 8; ++e)
    o[e] = (short)f2bf(bf2f((ushort)a[e]) * bf2f((ushort)b[e]));
  return o;
}

__device__ __forceinline__ void gload16(const void* g, void* l){
  __builtin_amdgcn_global_load_lds((const __attribute__((address_space(1))) unsigned*)g,
                                   (__attribute__((address_space(3))) unsigned*)l, 16, 0, 0);
}

__device__ __forceinline__ float wave_sum(float v){
  #pragma unroll
  for (int m = 32; m >= 1; m >>= 1) v += __shfl_xor(v, m);
  return v;
}
__device__ __forceinline__ float wave_max(float v){
  #pragma unroll
  for (int m = 32; m >= 1; m >>= 1) v = fmaxf(v, __shfl_xor(v, m));
  return v;
}

// ---------- merged prep ----------
#define SPAN_F4 524288        // 4096*512/4
#define IMG_F4  1179648       // 128*36*1024/4
#define CONV_BLKS ((SPAN_F4 + IMG_F4) / 256)   // 6656
#define TR_BLKS   (512 * 5)                    // 2560
__global__ void prep_all(const float* __restrict__ span, const float* __restrict__ img,
                         const float* __restrict__ b3,
                         const float* __restrict__ Wg, const float* __restrict__ W1,
                         const float* __restrict__ W2,
                         const float* __restrict__ sm, const float* __restrict__ im,
                         ushort* __restrict__ spbf, ushort* __restrict__ imgbf,
                         float* __restrict__ text,
                         ushort* __restrict__ WgT, ushort* __restrict__ UVBT,
                         ushort* __restrict__ W1cT, ushort* __restrict__ W2T,
                         float* cnt_s, float* cnt_i, int* iu, int* ju, float* loss){
  __shared__ float tile[32][33];
  const int bid = blockIdx.x, tid = threadIdx.x;
  if (bid < CONV_BLKS){
    int idx = bid * 256 + tid;
    if (idx < R_) text[idx] = b3[0];
    const float* src; ushort* dst; int k;
    if (idx < SPAN_F4){ src = span; dst = spbf; k = idx; }
    else              { src = img;  dst = imgbf; k = idx - SPAN_F4; }
    float4 v = *(const float4*)&src[(size_t)k * 4];
    ushort4 o; o.x = f2bf(v.x); o.y = f2bf(v.y); o.z = f2bf(v.z); o.w = f2bf(v.w);
    *(ushort4*)&dst[(size_t)k * 4] = o;
  } else if (bid < CONV_BLKS + TR_BLKS){
    int b = bid - CONV_BLKS;
    int z = b >> 9, rem = b & 511;
    int bx = rem & 31, by = rem >> 5;
    const float* src; ushort* dst; int Nn;
    if      (z == 0){ src = Wg;            dst = WgT;            Nn = 1024; }
    else if (z == 1){ src = W1;            dst = UVBT;           Nn = 512;  }
    else if (z == 2){ src = W1 + 512*512;  dst = UVBT + 512*512; Nn = 512;  }
    else if (z == 3){ src = W1 + 1024*512; dst = W1cT;           Nn = 512;  }
    else            { src = W2;            dst = W2T;            Nn = 512;  }
    if (bx * 32 >= Nn) return;
    int n0 = bx * 32, k0 = by * 32;
    int x = tid & 31, y = tid >> 5;   // 32 x 8
    #pragma unroll
    for (int i = 0; i < 4; ++i) tile[y + 8*i][x] = src[(k0 + y + 8*i) * Nn + n0 + x];
    __syncthreads();
    #pragma unroll
    for (int i = 0; i < 4; ++i) dst[(n0 + y + 8*i) * 512 + k0 + x] = f2bf(tile[x][y + 8*i]);
  } else {
    int t = (bid - CONV_BLKS - TR_BLKS) * 256 + tid;   // [0,512)
    if (t < P_){
      int i = 0, rem = t, cnt = N_ - 1;
      while (rem >= cnt){ rem -= cnt; ++i; --cnt; }
      iu[t] = i; ju[t] = i + 1 + rem;
    }
    if (t < B_){
      float s = 0.f;
      for (int n = 0; n < N_; ++n) s += sm[t*N_ + n];
      cnt_s[t] = s;
    } else if (t < 2*B_){
      int j = t - B_;
      float s = 0.f;
      for (int l = 0; l < L_; ++l) s += im[j*L_ + l];
      cnt_i[j] = s;
    }
    if (t == 0) loss[0] = 0.f;
  }
}

// ---------- BK=32 mainloop for span GEMMs ----------
__device__ __forceinline__ void mma_mainloop(const ushort* __restrict__ A,
                                             const ushort* __restrict__ BT,
                                             size_t m0, int n0,
                                             ushort* sA, ushort* sB, f32x4 acc[4][4]){
  const int tid = threadIdx.x, wid = tid >> 6, lane = tid & 63;
  const int wm = (wid >> 1) * 64, wn = (wid & 1) * 64;
  const int quad = lane >> 4, fm = lane & 15;
  const char* gA = (const char*)A + (m0 + (size_t)(wid * 32 + (lane >> 2))) * 1024 + (lane & 3) * 16;
  const char* gB = (const char*)BT + ((size_t)n0 + wid * 32 + (lane >> 2)) * 1024 + (lane & 3) * 16;
  ushort* lA = sA + wid * 32 * 32;
  ushort* lB = sB + wid * 32 * 32;
  #pragma unroll 1
  for (int ks = 0; ks < 16; ++ks){
    gload16(gA,             lA);
    gload16(gA + 16 * 1024, lA + 16 * 32);
    gload16(gB,             lB);
    gload16(gB + 16 * 1024, lB + 16 * 32);
    __syncthreads();
    bf16x8 af[4], bg[4];
    #pragma unroll
    for (int i = 0; i < 4; ++i){
      af[i] = *(const bf16x8*)&sA[(wm + i * 16 + fm) * 32 + quad * 8];
      bg[i] = *(const bf16x8*)&sB[(wn + i * 16 + fm) * 32 + quad * 8];
    }
    #pragma unroll
    for (int i = 0; i < 4; ++i)
      #pragma unroll
      for (int j = 0; j < 4; ++j)
        acc[i][j] = __builtin_amdgcn_mfma_f32_16x16x32_bf16(af[i], bg[j], acc[i][j], 0, 0, 0);
    __syncthreads();
    gA += 64; gB += 64;
  }
}

// Merged: span GEMMs + make_z
__global__ __launch_bounds__(256) void span2_makez(const ushort* __restrict__ A,
                                                   const ushort* __restrict__ BT2,
                                                   ushort* __restrict__ SG,
                                                   ushort* __restrict__ UV,
                                                   const int* __restrict__ iu,
                                                   const int* __restrict__ ju,
                                                   ushort* __restrict__ Z){
  __shared__ ushort sA[4096], sB[4096];
  if (blockIdx.x < 512){
    f32x4 acc[4][4] = {};
    size_t m0 = (size_t)(blockIdx.x >> 4) * 128;
    int ng = (blockIdx.x & 15) * 128;
    mma_mainloop(A, BT2, m0, ng, sA, sB, acc);
    const int tid = threadIdx.x, wid = tid >> 6, lane = tid & 63;
    const int wm = (wid >> 1) * 64, wn = (wid & 1) * 64, quad = lane >> 4, fm = lane & 15;
    ushort* C = (ng < 1024) ? SG : UV;
    const int nbase = (ng < 1024) ? ng : (ng - 1024);
    #pragma unroll
    for (int i = 0; i < 4; ++i)
      #pragma unroll
      for (int r = 0; r < 4; ++r){
        size_t row = m0 + wm + i * 16 + quad * 4 + r;
        #pragma unroll
        for (int j = 0; j < 4; ++j){
          int col = nbase + wn + j * 16 + fm;
          C[row * 1024 + col] = f2bf(acc[i][j][r]);
        }
      }
  } else {
    int idx = (blockIdx.x - 512) * 256 + threadIdx.x;  // 8 elems each
    int r = idx >> 6, k = (idx & 63) << 3;
    int b = r / P_, p = r - b * P_;
    bf16x8 x = *(const bf16x8*)&A[(size_t)(b * N_ + iu[p]) * 512 + k];
    bf16x8 y = *(const bf16x8*)&A[(size_t)(b * N_ + ju[p]) * 512 + k];
    *(bf16x8*)&Z[(size_t)r * 512 + k] = pkmul(x, y);
  }
}

// ---------- batched_m body (shared-memory passed in; 256 threads) ----------
__device__ void batched_m_body(const ushort* __restrict__ SGbf,
                               const ushort* __restrict__ imgbf,
                               const float* __restrict__ sm,
                               float* __restrict__ Mout,
                               float* __restrict__ Msum,
                               float* __restrict__ Mtot,
                               int b, float* red /*[4*32*48]*/, float* shr /*[4]*/){
  const int tid = threadIdx.x, wid = tid >> 6, lane = tid & 63;
  const int quad = lane >> 4, fm = lane & 15;
  f32x4 acc[2][3] = {};
  const int wk = wid * 256;
  const ushort* Ab = SGbf + (size_t)b * 32 * 1024;
  const ushort* Bb = imgbf + (size_t)b * 36 * 1024;
  #pragma unroll
  for (int ks = 0; ks < 8; ++ks){
    const int k = wk + ks * 32 + quad * 8;
    bf16x8 af[2], bg[3];
    af[0] = *(const bf16x8*)&Ab[(0*16 + fm) * 1024 + k];
    af[1] = *(const bf16x8*)&Ab[(1*16 + fm) * 1024 + k];
    bg[0] = *(const bf16x8*)&Bb[(0*16 + fm) * 1024 + k];
    bg[1] = *(const bf16x8*)&Bb[(1*16 + fm) * 1024 + k];
    bg[2] = *(const bf16x8*)&Bb[(2*16 + fm) * 1024 + k];  // rows 36..47 slack
    #pragma unroll
    for (int i = 0; i < 2; ++i)
      #pragma unroll
      for (int j = 0; j < 3; ++j)
        acc[i][j] = __builtin_amdgcn_mfma_f32_16x16x32_bf16(af[i], bg[j], acc[i][j], 0, 0, 0);
  }
  #pragma unroll
  for (int i = 0; i < 2; ++i)
    #pragma unroll
    for (int j = 0; j < 3; ++j)
      #pragma unroll
      for (int r = 0; r < 4; ++r)
        red[(wid * 32 + i*16 + quad*4 + r) * 48 + j*16 + fm] = acc[i][j][r];
  __syncthreads();
  float tot = 0.f;
  #pragma unroll
  for (int q = 0; q < 5; ++q){
    int out = tid + 256 * q;
    if (out < N_*L_){
      int n = out / L_, l = out - n * L_;
      float v = red[(0*32 + n)*48 + l] + red[(1*32 + n)*48 + l]
              + red[(2*32 + n)*48 + l] + red[(3*32 + n)*48 + l];
      Mout[b * (N_*L_) + out] = v;
      tot += v;
    }
  }
  tot = wave_sum(tot);
  if (lane == 0) shr[wid] = tot;
  __syncthreads();
  if (tid == 0) Mtot[b] = shr[0] + shr[1] + shr[2] + shr[3];
  if (tid < L_){
    float s = 0.f;
    for (int n = 0; n < N_; ++n){
      float mv = red[(0*32 + n)*48 + tid] + red[(1*32 + n)*48 + tid]
               + red[(2*32 + n)*48 + tid] + red[(3*32 + n)*48 + tid];
      s += mv * sm[b*N_ + n];
    }
    Msum[b*L_ + tid] = s;
  }
}

// ---------- lse_loss body (256 threads; waves 2,3 duplicate waves 0,1) ----------
__device__ void lse_loss_body(const float* __restrict__ Msum, const float* __restrict__ im,
                              const float* __restrict__ cnt_s, const float* __restrict__ cnt_i,
                              const float* __restrict__ Mtot, float* __restrict__ out,
                              int i, float* sh /*[4]*/){
  const int tid = threadIdx.x;
  const int t = tid & 127;            // waves 2,3 duplicate
  const int w4 = tid >> 6, lane = tid & 63;
  float sr = 0.f, sc = 0.f;
  #pragma unroll 4
  for (int l = 0; l < L_; ++l){
    sr += Msum[i*L_ + l] * im[t*L_ + l];
    sc += Msum[t*L_ + l] * im[i*L_ + l];
  }
  const float dr = cnt_s[i] * cnt_i[t];
  const float vr = (dr != 0.f) ? (sr / dr) : (Mtot[i] * (1.f/(float)(N_*L_)));
  const float dc = cnt_s[t] * cnt_i[i];
  const float vc = (dc != 0.f) ? (sc / dc) : (Mtot[t] * (1.f/(float)(N_*L_)));

  float m = wave_max(vr);
  if (lane == 0) sh[w4] = m;
  __syncthreads();
  const float mr = fmaxf(sh[0], sh[1]);
  __syncthreads();
  float e = wave_sum(expf(vr - mr));
  if (lane == 0) sh[w4] = e;
  __syncthreads();
  const float ser = sh[0] + sh[1];
  __syncthreads();
  float rs = wave_sum(vr);
  if (lane == 0) sh[w4] = rs;
  __syncthreads();
  const float rst = sh[0] + sh[1];
  __syncthreads();
  float mc0 = wave_max(vc);
  if (lane == 0) sh[w4] = mc0;
  __syncthreads();
  const float mc = fmaxf(sh[0], sh[1]);
  __syncthreads();
  float ec = wave_sum(expf(vc - mc));
  if (lane == 0) sh[w4] = ec;
  __syncthreads();
  const float sec = sh[0] + sh[1];
  if (tid == 0){
    float contrib = (mr + logf(ser)) + (mc + logf(sec)) - 2.f * rst / (float)B_;
    atomicAdd(out, contrib);
  }
}

// ---------- BK=64 mainloop (16x16x32; R11-proven) ----------
__device__ __forceinline__ void mma_loop_k64(const ushort* __restrict__ A,
                                             const ushort* __restrict__ BT,
                                             size_t m0, int n0,
                                             ushort* sA0, ushort* sA1,
                                             ushort* sB0, ushort* sB1,
                                             f32x4 acc[4][4]){
  const int tid = threadIdx.x, wid = tid >> 6, lane = tid & 63;
  const int wm = (wid >> 1) * 64, wn = (wid & 1) * 64;
  const int quad = lane >> 4, fm = lane & 15;
  const int r64 = tid >> 2, ch = (tid & 3) * 8;
  const ushort* gA = A + (m0 + r64) * 512 + ch;
  const ushort* gB = BT + (size_t)(n0 + r64) * 512 + ch;
  #pragma unroll 1
  for (int ks = 0; ks < 8; ++ks){
    const int k0 = ks * 64;
    gload16(gA + k0,                 sA0 + tid * 8);
    gload16(gA + 64 * 512 + k0,      sA0 + 2048 + tid * 8);
    gload16(gA + k0 + 32,            sA1 + tid * 8);
    gload16(gA + 64 * 512 + k0 + 32, sA1 + 2048 + tid * 8);
    gload16(gB + k0,                 sB0 + tid * 8);
    gload16(gB + 64 * 512 + k0,      sB0 + 2048 + tid * 8);
    gload16(gB + k0 + 32,            sB1 + tid * 8);
    gload16(gB + 64 * 512 + k0 + 32, sB1 + 2048 + tid * 8);
    __syncthreads();
    {
      bf16x8 af[4], bg[4];
      #pragma unroll
      for (int i = 0; i < 4; ++i){
        af[i] = *(const bf16x8*)&sA0[(wm + i * 16 + fm) * 32 + quad * 8];
        bg[i] = *(const bf16x8*)&sB0[(wn + i * 16 + fm) * 32 + quad * 8];
      }
      #pragma unroll
      for (int i = 0; i < 4; ++i)
        #pragma unroll
        for (int j = 0; j < 4; ++j)
          acc[i][j] = __builtin_amdgcn_mfma_f32_16x16x32_bf16(af[i], bg[j], acc[i][j], 0, 0, 0);
    }
    {
      bf16x8 af[4], bg[4];
      #pragma unroll
      for (int i = 0; i < 4; ++i){
        af[i] = *(const bf16x8*)&sA1[(wm + i * 16 + fm) * 32 + quad * 8];
        bg[i] = *(const bf16x8*)&sB1[(wn + i * 16 + fm) * 32 + quad * 8];
      }
      #pragma unroll
      for (int i = 0; i < 4; ++i)
        #pragma unroll
        for (int j = 0; j < 4; ++j)
          acc[i][j] = __builtin_amdgcn_mfma_f32_16x16x32_bf16(af[i], bg[j], acc[i][j], 0, 0, 0);
    }
    __syncthreads();
  }
}

// XCD-aware tile mapping (perf heuristic only)
__device__ __forceinline__ void tile_map(int bid, int& m0, int& n0){
  int x = bid & 7;
  int q = bid >> 3;        // 0..247
  int m = x * 62 + (q >> 2);
  m0 = m * 128;
  n0 = (q & 3) * 128;
}

// gemm_z dispatch: blocks 0..1983 = h1 GEMM; blocks 1984..2111 = batched_m
__global__ __launch_bounds__(256, 5) void gemm_z(const ushort* __restrict__ Z,
                                                 const ushort* __restrict__ W1cT,
                                                 const ushort* __restrict__ UV,
                                                 const float* __restrict__ b1,
                                                 const int* __restrict__ iu,
                                                 const int* __restrict__ ju,
                                                 ushort* __restrict__ h1,
                                                 const ushort* __restrict__ SGbf,
                                                 const ushort* __restrict__ imgbf,
                                                 const float* __restrict__ sm,
                                                 float* __restrict__ Mout,
                                                 float* __restrict__ Msum,
                                                 float* __restrict__ Mtot){
  __shared__ ushort smem[16384];   // 32 KB, aliased per role
  if (blockIdx.x >= GEMM_BLKS){
    float* red = (float*)smem;                 // 4*32*48 floats = 24576 B
    float* shr = red + 4*32*48;                // 16 B
    batched_m_body(SGbf, imgbf, sm, Mout, Msum, Mtot, blockIdx.x - GEMM_BLKS, red, shr);
    return;
  }
  ushort* sA0 = smem;
  ushort* sA1 = smem + 4096;
  ushort* sB0 = smem + 8192;
  ushort* sB1 = smem + 12288;
  f32x4 acc[4][4] = {};
  int m0i, n0; tile_map(blockIdx.x, m0i, n0);
  const size_t m0 = (size_t)m0i;
  mma_loop_k64(Z, W1cT, m0, n0, sA0, sA1, sB0, sB1, acc);
  const int tid = threadIdx.x, wid = tid >> 6, lane = tid & 63;
  const int wm = (wid >> 1) * 64, wn = (wid & 1) * 64, quad = lane >> 4, fm = lane & 15;
  #pragma unroll
  for (int i = 0; i < 4; ++i)
    #pragma unroll
    for (int r = 0; r < 4; ++r){
      int row = (int)m0 + wm + i * 16 + quad * 4 + r;
      int b = row / P_, p = row - b * P_;
      const ushort* Ur = UV + (size_t)(b * N_ + iu[p]) * 1024;
      const ushort* Vr = UV + (size_t)(b * N_ + ju[p]) * 1024 + 512;
      #pragma unroll
      for (int j = 0; j < 4; ++j){
        int col = n0 + wn + j * 16 + fm;
        float h = acc[i][j][r] + bf2f(Ur[col]) + bf2f(Vr[col]) + b1[col];
        h1[(size_t)row * 512 + col] = f2bf(fmaxf(h, 0.f));
      }
    }
}

// gemm_h2 dispatch: blocks 0..1983 = text GEMM; blocks 1984..2111 = lse_loss
__global__ __launch_bounds__(256, 5) void gemm_h2(const ushort* __restrict__ h1,
                                                  const ushort* __restrict__ W2T,
                                                  const float* __restrict__ b2,
                                                  const float* __restrict__ W3,
                                                  float* __restrict__ text,
                                                  const float* __restrict__ Msum,
                                                  const float* __restrict__ im,
                                                  const float* __restrict__ cnt_s,
                                                  const float* __restrict__ cnt_i,
                                                  const float* __restrict__ Mtot,
                                                  float* __restrict__ loss){
  __shared__ ushort smem[16384];   // 32 KB, aliased per role
  if (blockIdx.x >= GEMM_BLKS){
    lse_loss_body(Msum, im, cnt_s, cnt_i, Mtot, loss, blockIdx.x - GEMM_BLKS, (float*)smem);
    return;
  }
  ushort* sA0 = smem;
  ushort* sA1 = smem + 4096;
  ushort* sB0 = smem + 8192;
  ushort* sB1 = smem + 12288;
  f32x4 acc[4][4] = {};
  int m0i, n0; tile_map(blockIdx.x, m0i, n0);
  const size_t m0 = (size_t)m0i;
  mma_loop_k64(h1, W2T, m0, n0, sA0, sA1, sB0, sB1, acc);
  const int tid = threadIdx.x, wid = tid >> 6, lane = tid & 63;
  const int wm = (wid >> 1) * 64, wn = (wid & 1) * 64, quad = lane >> 4, fm = lane & 15;
  float w3v[4], b2v[4];
  #pragma unroll
  for (int j = 0; j < 4; ++j){
    int col = n0 + wn + j * 16 + fm;
    w3v[j] = W3[col]; b2v[j] = b2[col];
  }
  #pragma unroll
  for (int i = 0; i < 4; ++i)
    #pragma unroll
    for (int r = 0; r < 4; ++r){
      int row = (int)m0 + wm + i * 16 + quad * 4 + r;
      float s = 0.f;
      #pragma unroll
      for (int j = 0; j < 4; ++j){
        float h = fmaxf(acc[i][j][r] + b2v[j], 0.f);
        s = fmaf(h, w3v[j], s);
      }
      s += __shfl_xor(s, 1); s += __shfl_xor(s, 2); s += __shfl_xor(s, 4); s += __shfl_xor(s, 8);
      if (fm == 0) atomicAdd(&text[row], s);
    }
}

extern "C" void kernel_launch(void* const* d_in, const int* in_sizes, int n_in,
                              void* d_out, int out_size, void* d_ws, size_t ws_size,
                              hipStream_t stream) {
  const float* span = (const float*)d_in[0];
  const float* img  = (const float*)d_in[1];
  const float* sm   = (const float*)d_in[2];
  const float* im   = (const float*)d_in[3];
  const float* Wg   = (const float*)d_in[4];
  const float* W1   = (const float*)d_in[5];
  const float* b1   = (const float*)d_in[6];
  const float* W2   = (const float*)d_in[7];
  const float* b2   = (const float*)d_in[8];
  const float* W3   = (const float*)d_in[9];
  const float* b3   = (const float*)d_in[10];

  float* out  = (float*)d_out;
  float* loss = out;
  float* Mout = out + 1;
  float* text = out + 1 + B_*N_*L_;

  ushort* wsu  = (ushort*)d_ws;
  ushort* Zbf  = wsu;                          // R_*512
  ushort* h1bf = Zbf + (size_t)R_*512;         // R_*512
  ushort* UVbf = h1bf + (size_t)R_*512;        // 4096*1024
  ushort* SGbf = UVbf + (size_t)4096*1024;     // 4096*1024
  ushort* spbf = SGbf + (size_t)4096*1024;     // 4096*512
  ushort* imgbf= spbf + 4096*512;              // (128*36+12)*1024
  ushort* BT2  = imgbf + (size_t)(B_*L_ + 12)*1024; // WgT then UVBT
  ushort* WgT  = BT2;
  ushort* UVBT = BT2 + 1024*512;
  ushort* W1cT = UVBT + 1024*512;              // 512*512
  ushort* W2T  = W1cT + 512*512;               // 512*512
  float* Msum  = (float*)(W2T + 512*512);      // 4608
  float* Mtot  = Msum + B_*L_;
  float* cnt_s = Mtot + B_;
  float* cnt_i = cnt_s + B_;
  int*   iu    = (int*)(cnt_i + B_);           // 496
  int*   ju    = iu + P_;                      // 496

  prep_all<<<CONV_BLKS + TR_BLKS + 2, 256, 0, stream>>>(
      span, img, b3, Wg, W1, W2, sm, im,
      spbf, imgbf, text, WgT, UVBT, W1cT, W2T, cnt_s, cnt_i, iu, ju, loss);

  // span GEMMs + make_z in one dispatch
  span2_makez<<<512 + R_*512/8/256, 256, 0, stream>>>(spbf, BT2, SGbf, UVbf, iu, ju, Zbf);

  // gemm_z + batched_m (block-specialized)
  gemm_z<<<GEMM_BLKS + B_, 256, 0, stream>>>(
      Zbf, W1cT, UVbf, b1, iu, ju, h1bf, SGbf, imgbf, sm, Mout, Msum, Mtot);

  // gemm_h2 + lse_loss (block-specialized)
  gemm_h2<<<GEMM_BLKS + B_, 256, 0, stream>>>(
      h1bf, W2T, b2, W3, text, Msum, im, cnt_s, cnt_i, Mtot, loss);
}

// Round 14
// 247.314 us; speedup vs baseline: 1.1365x; 1.0834x over previous
//
#include <hip/hip_runtime.h>

#define B_  128
#define N_  32
#define L_  36
#define DS  512
#define DV  1024
#define H_  512
#define P_  496
#define R_  63488      // B_*P_
#define LSE_BLKS 128   // prepended to gemm_h2 dispatch

typedef __attribute__((ext_vector_type(8))) short bf16x8;
typedef __attribute__((ext_vector_type(4))) float f32x4;

__device__ __forceinline__ ushort f2bf(float x){
  unsigned u = __builtin_bit_cast(unsigned, x);
  return (ushort)((u + 0x7FFFu + ((u >> 16) & 1u)) >> 16);
}
__device__ __forceinline__ float bf2f(ushort u){
  unsigned v = ((unsigned)u) << 16;
  return __builtin_bit_cast(float, v);
}

__device__ __forceinline__ bf16x8 pkmul(bf16x8 a, bf16x8 b){
  bf16x8 o;
  #pragma unroll
  for (int e = 0; e < 8; ++e)
    o[e] = (short)f2bf(bf2f((ushort)a[e]) * bf2f((ushort)b[e]));
  return o;
}

__device__ __forceinline__ void gload16(const void* g, void* l){
  __builtin_amdgcn_global_load_lds((const __attribute__((address_space(1))) unsigned*)g,
                                   (__attribute__((address_space(3))) unsigned*)l, 16, 0, 0);
}

__device__ __forceinline__ float wave_sum(float v){
  #pragma unroll
  for (int m = 32; m >= 1; m >>= 1) v += __shfl_xor(v, m);
  return v;
}
__device__ __forceinline__ float wave_max(float v){
  #pragma unroll
  for (int m = 32; m >= 1; m >>= 1) v = fmaxf(v, __shfl_xor(v, m));
  return v;
}

// ---------- merged prep ----------
#define SPAN_F4 524288        // 4096*512/4
#define IMG_F4  1179648       // 128*36*1024/4
#define CONV_BLKS ((SPAN_F4 + IMG_F4) / 256)   // 6656
#define TR_BLKS   (512 * 5)                    // 2560
__global__ void prep_all(const float* __restrict__ span, const float* __restrict__ img,
                         const float* __restrict__ b3,
                         const float* __restrict__ Wg, const float* __restrict__ W1,
                         const float* __restrict__ W2,
                         const float* __restrict__ sm, const float* __restrict__ im,
                         ushort* __restrict__ spbf, ushort* __restrict__ imgbf,
                         float* __restrict__ text,
                         ushort* __restrict__ WgT, ushort* __restrict__ UVBT,
                         ushort* __restrict__ W1cT, ushort* __restrict__ W2T,
                         float* cnt_s, float* cnt_i, int* iu, int* ju, float* loss){
  __shared__ float tile[32][33];
  const int bid = blockIdx.x, tid = threadIdx.x;
  if (bid < CONV_BLKS){
    int idx = bid * 256 + tid;
    if (idx < R_) text[idx] = b3[0];
    const float* src; ushort* dst; int k;
    if (idx < SPAN_F4){ src = span; dst = spbf; k = idx; }
    else              { src = img;  dst = imgbf; k = idx - SPAN_F4; }
    float4 v = *(const float4*)&src[(size_t)k * 4];
    ushort4 o; o.x = f2bf(v.x); o.y = f2bf(v.y); o.z = f2bf(v.z); o.w = f2bf(v.w);
    *(ushort4*)&dst[(size_t)k * 4] = o;
  } else if (bid < CONV_BLKS + TR_BLKS){
    int b = bid - CONV_BLKS;
    int z = b >> 9, rem = b & 511;
    int bx = rem & 31, by = rem >> 5;
    const float* src; ushort* dst; int Nn;
    if      (z == 0){ src = Wg;            dst = WgT;            Nn = 1024; }
    else if (z == 1){ src = W1;            dst = UVBT;           Nn = 512;  }
    else if (z == 2){ src = W1 + 512*512;  dst = UVBT + 512*512; Nn = 512;  }
    else if (z == 3){ src = W1 + 1024*512; dst = W1cT;           Nn = 512;  }
    else            { src = W2;            dst = W2T;            Nn = 512;  }
    if (bx * 32 >= Nn) return;
    int n0 = bx * 32, k0 = by * 32;
    int x = tid & 31, y = tid >> 5;   // 32 x 8
    #pragma unroll
    for (int i = 0; i < 4; ++i) tile[y + 8*i][x] = src[(k0 + y + 8*i) * Nn + n0 + x];
    __syncthreads();
    #pragma unroll
    for (int i = 0; i < 4; ++i) dst[(n0 + y + 8*i) * 512 + k0 + x] = f2bf(tile[x][y + 8*i]);
  } else {
    int t = (bid - CONV_BLKS - TR_BLKS) * 256 + tid;   // [0,512)
    if (t < P_){
      int i = 0, rem = t, cnt = N_ - 1;
      while (rem >= cnt){ rem -= cnt; ++i; --cnt; }
      iu[t] = i; ju[t] = i + 1 + rem;
    }
    if (t < B_){
      float s = 0.f;
      for (int n = 0; n < N_; ++n) s += sm[t*N_ + n];
      cnt_s[t] = s;
    } else if (t < 2*B_){
      int j = t - B_;
      float s = 0.f;
      for (int l = 0; l < L_; ++l) s += im[j*L_ + l];
      cnt_i[j] = s;
    }
    if (t == 0) loss[0] = 0.f;
  }
}

// ---------- BK=32 mainloop for span GEMMs ----------
__device__ __forceinline__ void mma_mainloop(const ushort* __restrict__ A,
                                             const ushort* __restrict__ BT,
                                             size_t m0, int n0,
                                             ushort* sA, ushort* sB, f32x4 acc[4][4]){
  const int tid = threadIdx.x, wid = tid >> 6, lane = tid & 63;
  const int wm = (wid >> 1) * 64, wn = (wid & 1) * 64;
  const int quad = lane >> 4, fm = lane & 15;
  const char* gA = (const char*)A + (m0 + (size_t)(wid * 32 + (lane >> 2))) * 1024 + (lane & 3) * 16;
  const char* gB = (const char*)BT + ((size_t)n0 + wid * 32 + (lane >> 2)) * 1024 + (lane & 3) * 16;
  ushort* lA = sA + wid * 32 * 32;
  ushort* lB = sB + wid * 32 * 32;
  #pragma unroll 1
  for (int ks = 0; ks < 16; ++ks){
    gload16(gA,             lA);
    gload16(gA + 16 * 1024, lA + 16 * 32);
    gload16(gB,             lB);
    gload16(gB + 16 * 1024, lB + 16 * 32);
    __syncthreads();
    bf16x8 af[4], bg[4];
    #pragma unroll
    for (int i = 0; i < 4; ++i){
      af[i] = *(const bf16x8*)&sA[(wm + i * 16 + fm) * 32 + quad * 8];
      bg[i] = *(const bf16x8*)&sB[(wn + i * 16 + fm) * 32 + quad * 8];
    }
    #pragma unroll
    for (int i = 0; i < 4; ++i)
      #pragma unroll
      for (int j = 0; j < 4; ++j)
        acc[i][j] = __builtin_amdgcn_mfma_f32_16x16x32_bf16(af[i], bg[j], acc[i][j], 0, 0, 0);
    __syncthreads();
    gA += 64; gB += 64;
  }
}

// Merged: span GEMMs + make_z
__global__ __launch_bounds__(256) void span2_makez(const ushort* __restrict__ A,
                                                   const ushort* __restrict__ BT2,
                                                   ushort* __restrict__ SG,
                                                   ushort* __restrict__ UV,
                                                   const int* __restrict__ iu,
                                                   const int* __restrict__ ju,
                                                   ushort* __restrict__ Z){
  __shared__ ushort sA[4096], sB[4096];
  if (blockIdx.x < 512){
    f32x4 acc[4][4] = {};
    size_t m0 = (size_t)(blockIdx.x >> 4) * 128;
    int ng = (blockIdx.x & 15) * 128;
    mma_mainloop(A, BT2, m0, ng, sA, sB, acc);
    const int tid = threadIdx.x, wid = tid >> 6, lane = tid & 63;
    const int wm = (wid >> 1) * 64, wn = (wid & 1) * 64, quad = lane >> 4, fm = lane & 15;
    ushort* C = (ng < 1024) ? SG : UV;
    const int nbase = (ng < 1024) ? ng : (ng - 1024);
    #pragma unroll
    for (int i = 0; i < 4; ++i)
      #pragma unroll
      for (int r = 0; r < 4; ++r){
        size_t row = m0 + wm + i * 16 + quad * 4 + r;
        #pragma unroll
        for (int j = 0; j < 4; ++j){
          int col = nbase + wn + j * 16 + fm;
          C[row * 1024 + col] = f2bf(acc[i][j][r]);
        }
      }
  } else {
    int idx = (blockIdx.x - 512) * 256 + threadIdx.x;  // 8 elems each
    int r = idx >> 6, k = (idx & 63) << 3;
    int b = r / P_, p = r - b * P_;
    bf16x8 x = *(const bf16x8*)&A[(size_t)(b * N_ + iu[p]) * 512 + k];
    bf16x8 y = *(const bf16x8*)&A[(size_t)(b * N_ + ju[p]) * 512 + k];
    *(bf16x8*)&Z[(size_t)r * 512 + k] = pkmul(x, y);
  }
}

// M[b] = SGbf[b] @ imgbf[b]^T; also Msum[b,:] and Mtot[b]  (standalone)
__global__ __launch_bounds__(256) void batched_m_mfma(const ushort* __restrict__ SGbf,
                                                      const ushort* __restrict__ imgbf,
                                                      const float* __restrict__ sm,
                                                      float* __restrict__ Mout,
                                                      float* __restrict__ Msum,
                                                      float* __restrict__ Mtot){
  const int b = blockIdx.x;
  const int tid = threadIdx.x, wid = tid >> 6, lane = tid & 63;
  const int quad = lane >> 4, fm = lane & 15;
  __shared__ float red[4][32][48];
  __shared__ float shr[4];
  f32x4 acc[2][3] = {};
  const int wk = wid * 256;
  const ushort* Ab = SGbf + (size_t)b * 32 * 1024;
  const ushort* Bb = imgbf + (size_t)b * 36 * 1024;
  #pragma unroll
  for (int ks = 0; ks < 8; ++ks){
    const int k = wk + ks * 32 + quad * 8;
    bf16x8 af[2], bg[3];
    af[0] = *(const bf16x8*)&Ab[(0*16 + fm) * 1024 + k];
    af[1] = *(const bf16x8*)&Ab[(1*16 + fm) * 1024 + k];
    bg[0] = *(const bf16x8*)&Bb[(0*16 + fm) * 1024 + k];
    bg[1] = *(const bf16x8*)&Bb[(1*16 + fm) * 1024 + k];
    bg[2] = *(const bf16x8*)&Bb[(2*16 + fm) * 1024 + k];  // rows 36..47 slack
    #pragma unroll
    for (int i = 0; i < 2; ++i)
      #pragma unroll
      for (int j = 0; j < 3; ++j)
        acc[i][j] = __builtin_amdgcn_mfma_f32_16x16x32_bf16(af[i], bg[j], acc[i][j], 0, 0, 0);
  }
  #pragma unroll
  for (int i = 0; i < 2; ++i)
    #pragma unroll
    for (int j = 0; j < 3; ++j)
      #pragma unroll
      for (int r = 0; r < 4; ++r)
        red[wid][i*16 + quad*4 + r][j*16 + fm] = acc[i][j][r];
  __syncthreads();
  float tot = 0.f;
  #pragma unroll
  for (int q = 0; q < 5; ++q){
    int out = tid + 256 * q;
    if (out < N_*L_){
      int n = out / L_, l = out - n * L_;
      float v = red[0][n][l] + red[1][n][l] + red[2][n][l] + red[3][n][l];
      Mout[b * (N_*L_) + out] = v;
      tot += v;
    }
  }
  tot = wave_sum(tot);
  if (lane == 0) shr[wid] = tot;
  __syncthreads();
  if (tid == 0) Mtot[b] = shr[0] + shr[1] + shr[2] + shr[3];
  if (tid < L_){
    float s = 0.f;
    for (int n = 0; n < N_; ++n){
      float mv = red[0][n][tid] + red[1][n][tid] + red[2][n][tid] + red[3][n][tid];
      s += mv * sm[b*N_ + n];
    }
    Msum[b*L_ + tid] = s;
  }
}

// ---------- lse_loss body (256 threads; waves 2,3 duplicate waves 0,1) ----------
__device__ void lse_loss_body(const float* __restrict__ Msum, const float* __restrict__ im,
                              const float* __restrict__ cnt_s, const float* __restrict__ cnt_i,
                              const float* __restrict__ Mtot, float* __restrict__ out,
                              int i, float* sh /*[4]*/){
  const int tid = threadIdx.x;
  const int t = tid & 127;            // waves 2,3 duplicate
  const int w4 = tid >> 6, lane = tid & 63;
  float sr = 0.f, sc = 0.f;
  #pragma unroll 4
  for (int l = 0; l < L_; ++l){
    sr += Msum[i*L_ + l] * im[t*L_ + l];
    sc += Msum[t*L_ + l] * im[i*L_ + l];
  }
  const float dr = cnt_s[i] * cnt_i[t];
  const float vr = (dr != 0.f) ? (sr / dr) : (Mtot[i] * (1.f/(float)(N_*L_)));
  const float dc = cnt_s[t] * cnt_i[i];
  const float vc = (dc != 0.f) ? (sc / dc) : (Mtot[t] * (1.f/(float)(N_*L_)));

  float m = wave_max(vr);
  if (lane == 0) sh[w4] = m;
  __syncthreads();
  const float mr = fmaxf(sh[0], sh[1]);
  __syncthreads();
  float e = wave_sum(expf(vr - mr));
  if (lane == 0) sh[w4] = e;
  __syncthreads();
  const float ser = sh[0] + sh[1];
  __syncthreads();
  float rs = wave_sum(vr);
  if (lane == 0) sh[w4] = rs;
  __syncthreads();
  const float rst = sh[0] + sh[1];
  __syncthreads();
  float mc0 = wave_max(vc);
  if (lane == 0) sh[w4] = mc0;
  __syncthreads();
  const float mc = fmaxf(sh[0], sh[1]);
  __syncthreads();
  float ec = wave_sum(expf(vc - mc));
  if (lane == 0) sh[w4] = ec;
  __syncthreads();
  const float sec = sh[0] + sh[1];
  if (tid == 0){
    float contrib = (mr + logf(ser)) + (mc + logf(sec)) - 2.f * rst / (float)B_;
    atomicAdd(out, contrib);
  }
}

// ---------- BK=64 mainloop (16x16x32; R11-proven) ----------
__device__ __forceinline__ void mma_loop_k64(const ushort* __restrict__ A,
                                             const ushort* __restrict__ BT,
                                             size_t m0, int n0,
                                             ushort* sA0, ushort* sA1,
                                             ushort* sB0, ushort* sB1,
                                             f32x4 acc[4][4]){
  const int tid = threadIdx.x, wid = tid >> 6, lane = tid & 63;
  const int wm = (wid >> 1) * 64, wn = (wid & 1) * 64;
  const int quad = lane >> 4, fm = lane & 15;
  const int r64 = tid >> 2, ch = (tid & 3) * 8;
  const ushort* gA = A + (m0 + r64) * 512 + ch;
  const ushort* gB = BT + (size_t)(n0 + r64) * 512 + ch;
  #pragma unroll 1
  for (int ks = 0; ks < 8; ++ks){
    const int k0 = ks * 64;
    gload16(gA + k0,                 sA0 + tid * 8);
    gload16(gA + 64 * 512 + k0,      sA0 + 2048 + tid * 8);
    gload16(gA + k0 + 32,            sA1 + tid * 8);
    gload16(gA + 64 * 512 + k0 + 32, sA1 + 2048 + tid * 8);
    gload16(gB + k0,                 sB0 + tid * 8);
    gload16(gB + 64 * 512 + k0,      sB0 + 2048 + tid * 8);
    gload16(gB + k0 + 32,            sB1 + tid * 8);
    gload16(gB + 64 * 512 + k0 + 32, sB1 + 2048 + tid * 8);
    __syncthreads();
    {
      bf16x8 af[4], bg[4];
      #pragma unroll
      for (int i = 0; i < 4; ++i){
        af[i] = *(const bf16x8*)&sA0[(wm + i * 16 + fm) * 32 + quad * 8];
        bg[i] = *(const bf16x8*)&sB0[(wn + i * 16 + fm) * 32 + quad * 8];
      }
      #pragma unroll
      for (int i = 0; i < 4; ++i)
        #pragma unroll
        for (int j = 0; j < 4; ++j)
          acc[i][j] = __builtin_amdgcn_mfma_f32_16x16x32_bf16(af[i], bg[j], acc[i][j], 0, 0, 0);
    }
    {
      bf16x8 af[4], bg[4];
      #pragma unroll
      for (int i = 0; i < 4; ++i){
        af[i] = *(const bf16x8*)&sA1[(wm + i * 16 + fm) * 32 + quad * 8];
        bg[i] = *(const bf16x8*)&sB1[(wn + i * 16 + fm) * 32 + quad * 8];
      }
      #pragma unroll
      for (int i = 0; i < 4; ++i)
        #pragma unroll
        for (int j = 0; j < 4; ++j)
          acc[i][j] = __builtin_amdgcn_mfma_f32_16x16x32_bf16(af[i], bg[j], acc[i][j], 0, 0, 0);
    }
    __syncthreads();
  }
}

// XCD-aware tile mapping (perf heuristic only)
__device__ __forceinline__ void tile_map(int bid, int& m0, int& n0){
  int x = bid & 7;
  int q = bid >> 3;        // 0..247
  int m = x * 62 + (q >> 2);
  m0 = m * 128;
  n0 = (q & 3) * 128;
}

// h1 = relu(Z@W1c + U + V + b1), bf16 out. 128x128 tile, BK=64. (R11-exact)
__global__ __launch_bounds__(256, 5) void gemm_z(const ushort* __restrict__ Z,
                                                 const ushort* __restrict__ W1cT,
                                                 const ushort* __restrict__ UV,
                                                 const float* __restrict__ b1,
                                                 const int* __restrict__ iu,
                                                 const int* __restrict__ ju,
                                                 ushort* __restrict__ h1){
  __shared__ ushort sA0[4096], sA1[4096], sB0[4096], sB1[4096];  // 32 KB
  f32x4 acc[4][4] = {};
  int m0i, n0; tile_map(blockIdx.x, m0i, n0);
  const size_t m0 = (size_t)m0i;
  mma_loop_k64(Z, W1cT, m0, n0, sA0, sA1, sB0, sB1, acc);
  const int tid = threadIdx.x, wid = tid >> 6, lane = tid & 63;
  const int wm = (wid >> 1) * 64, wn = (wid & 1) * 64, quad = lane >> 4, fm = lane & 15;
  #pragma unroll
  for (int i = 0; i < 4; ++i)
    #pragma unroll
    for (int r = 0; r < 4; ++r){
      int row = (int)m0 + wm + i * 16 + quad * 4 + r;
      int b = row / P_, p = row - b * P_;
      const ushort* Ur = UV + (size_t)(b * N_ + iu[p]) * 1024;
      const ushort* Vr = UV + (size_t)(b * N_ + ju[p]) * 1024 + 512;
      #pragma unroll
      for (int j = 0; j < 4; ++j){
        int col = n0 + wn + j * 16 + fm;
        float h = acc[i][j][r] + bf2f(Ur[col]) + bf2f(Vr[col]) + b1[col];
        h1[(size_t)row * 512 + col] = f2bf(fmaxf(h, 0.f));
      }
    }
}

// gemm_h2 dispatch: blocks 0..127 = lse_loss (prepended, inputs ready); 128..2111 = text GEMM
__global__ __launch_bounds__(256, 5) void gemm_h2(const ushort* __restrict__ h1,
                                                  const ushort* __restrict__ W2T,
                                                  const float* __restrict__ b2,
                                                  const float* __restrict__ W3,
                                                  float* __restrict__ text,
                                                  const float* __restrict__ Msum,
                                                  const float* __restrict__ im,
                                                  const float* __restrict__ cnt_s,
                                                  const float* __restrict__ cnt_i,
                                                  const float* __restrict__ Mtot,
                                                  float* __restrict__ loss){
  __shared__ ushort smem[16384];   // 32 KB
  if (blockIdx.x < LSE_BLKS){
    lse_loss_body(Msum, im, cnt_s, cnt_i, Mtot, loss, blockIdx.x, (float*)smem);
    return;
  }
  ushort* sA0 = smem;
  ushort* sA1 = smem + 4096;
  ushort* sB0 = smem + 8192;
  ushort* sB1 = smem + 12288;
  f32x4 acc[4][4] = {};
  int m0i, n0; tile_map(blockIdx.x - LSE_BLKS, m0i, n0);
  const size_t m0 = (size_t)m0i;
  mma_loop_k64(h1, W2T, m0, n0, sA0, sA1, sB0, sB1, acc);
  const int tid = threadIdx.x, wid = tid >> 6, lane = tid & 63;
  const int wm = (wid >> 1) * 64, wn = (wid & 1) * 64, quad = lane >> 4, fm = lane & 15;
  float w3v[4], b2v[4];
  #pragma unroll
  for (int j = 0; j < 4; ++j){
    int col = n0 + wn + j * 16 + fm;
    w3v[j] = W3[col]; b2v[j] = b2[col];
  }
  #pragma unroll
  for (int i = 0; i < 4; ++i)
    #pragma unroll
    for (int r = 0; r < 4; ++r){
      int row = (int)m0 + wm + i * 16 + quad * 4 + r;
      float s = 0.f;
      #pragma unroll
      for (int j = 0; j < 4; ++j){
        float h = fmaxf(acc[i][j][r] + b2v[j], 0.f);
        s = fmaf(h, w3v[j], s);
      }
      s += __shfl_xor(s, 1); s += __shfl_xor(s, 2); s += __shfl_xor(s, 4); s += __shfl_xor(s, 8);
      if (fm == 0) atomicAdd(&text[row], s);
    }
}

extern "C" void kernel_launch(void* const* d_in, const int* in_sizes, int n_in,
                              void* d_out, int out_size, void* d_ws, size_t ws_size,
                              hipStream_t stream) {
  const float* span = (const float*)d_in[0];
  const float* img  = (const float*)d_in[1];
  const float* sm   = (const float*)d_in[2];
  const float* im   = (const float*)d_in[3];
  const float* Wg   = (const float*)d_in[4];
  const float* W1   = (const float*)d_in[5];
  const float* b1   = (const float*)d_in[6];
  const float* W2   = (const float*)d_in[7];
  const float* b2   = (const float*)d_in[8];
  const float* W3   = (const float*)d_in[9];
  const float* b3   = (const float*)d_in[10];

  float* out  = (float*)d_out;
  float* loss = out;
  float* Mout = out + 1;
  float* text = out + 1 + B_*N_*L_;

  ushort* wsu  = (ushort*)d_ws;
  ushort* Zbf  = wsu;                          // R_*512
  ushort* h1bf = Zbf + (size_t)R_*512;         // R_*512
  ushort* UVbf = h1bf + (size_t)R_*512;        // 4096*1024
  ushort* SGbf = UVbf + (size_t)4096*1024;     // 4096*1024
  ushort* spbf = SGbf + (size_t)4096*1024;     // 4096*512
  ushort* imgbf= spbf + 4096*512;              // (128*36+12)*1024
  ushort* BT2  = imgbf + (size_t)(B_*L_ + 12)*1024; // WgT then UVBT
  ushort* WgT  = BT2;
  ushort* UVBT = BT2 + 1024*512;
  ushort* W1cT = UVBT + 1024*512;              // 512*512
  ushort* W2T  = W1cT + 512*512;               // 512*512
  float* Msum  = (float*)(W2T + 512*512);      // 4608
  float* Mtot  = Msum + B_*L_;
  float* cnt_s = Mtot + B_;
  float* cnt_i = cnt_s + B_;
  int*   iu    = (int*)(cnt_i + B_);           // 496
  int*   ju    = iu + P_;                      // 496

  prep_all<<<CONV_BLKS + TR_BLKS + 2, 256, 0, stream>>>(
      span, img, b3, Wg, W1, W2, sm, im,
      spbf, imgbf, text, WgT, UVBT, W1cT, W2T, cnt_s, cnt_i, iu, ju, loss);

  // span GEMMs + make_z in one dispatch
  span2_makez<<<512 + R_*512/8/256, 256, 0, stream>>>(spbf, BT2, SGbf, UVbf, iu, ju, Zbf);

  // M path
  batched_m_mfma<<<B_, 256, 0, stream>>>(SGbf, imgbf, sm, Mout, Msum, Mtot);

  // text path: gemm_z (clean), then gemm_h2 with lse_loss prepended
  gemm_z<<<1984, 256, 0, stream>>>(Zbf, W1cT, UVbf, b1, iu, ju, h1bf);
  gemm_h2<<<LSE_BLKS + 1984, 256, 0, stream>>>(
      h1bf, W2T, b2, W3, text, Msum, im, cnt_s, cnt_i, Mtot, loss);
}